// Round 1
// 532.381 us; speedup vs baseline: 1.1939x; 1.1939x over previous
//
#include <hip/hip_runtime.h>
#include <stdint.h>

// ---------------------------------------------------------------------------
// OrthoLinear: out[b,s,o] = sum_k x[b,s,k] * (dequant(base_packed,scales)[o,k]
//                                             + w_ortho[o,k])
// M = B*S = 8192, N = OUT = 4096, K = IN = 4096, fp32 in/out.
// R4: GEMM ported to the 256x256 8-phase template (T2+T3+T4+T5).
//   - 512 threads = 8 waves (2M x 4N), per-wave 128x64 output, acc[8][4].
//   - LDS: 4-deep ring of 32-wide K-slices per matrix (4 x 16 KB x 2 = 128 KB).
//   - Per slice: phase A {8 ds_read_b128 + stage A-half + bar + lgkmcnt(0) +
//     16 MFMA}, phase B {4 ds_read + stage B-half + bar + lgkmcnt(0) + 16 MFMA
//     + counted vmcnt}. Staging runs 3 slices ahead; steady-state wait is
//     vmcnt(8) (2 slices x 4 loads in flight), never 0 in the main loop.
//   - Ring safety: slice s+4 overwrites slot(s) and is issued only in phases
//     after the end-of-slice-s barrier (reads of slot(s) complete before it).
//   - Same XOR chunk swizzle as R3 (measured 0 bank conflicts): store chunk
//     c^( (row>>1)&3 ), pre-swizzled global source for linear gload_lds dest.
// ---------------------------------------------------------------------------

#define M_TOTAL 8192
#define N_TOTAL 4096
#define K_TOTAL 4096

typedef __attribute__((ext_vector_type(8)))  __bf16          bf16x8;   // MFMA A/B frag (4 VGPRs)
typedef __attribute__((ext_vector_type(4)))  float           floatx4;  // MFMA C/D frag
typedef __attribute__((ext_vector_type(8)))  unsigned short  ushort8;
typedef __attribute__((ext_vector_type(4)))  float           f32x4;
typedef __attribute__((ext_vector_type(4)))  int             intx4;

// fp32 -> bf16 round-to-nearest-even (data has no NaN)
__device__ __forceinline__ unsigned short f2bf(float f) {
    union { float f; uint32_t u; } c; c.f = f;
    uint32_t u = c.u + 0x7FFFu + ((c.u >> 16) & 1u);
    return (unsigned short)(u >> 16);
}

// ---------------------------------------------------------------------------
// Merged prep (unchanged from R3): blocks [0, 16384) convert x fp32->bf16;
// blocks [16384, 24576) dequant W: (nibble-8)*scale + ortho -> bf16.
// ---------------------------------------------------------------------------
#define CVT_BLOCKS 16384
#define DEQ_BLOCKS 8192

__global__ __launch_bounds__(256) void prep_kernel(
    const float* __restrict__ x,        // [M, K] fp32
    const int*   __restrict__ packed,   // [N, K/2] nibble-packed
    const float* __restrict__ scales,   // [N]
    const float* __restrict__ ortho,    // [N, K] fp32
    unsigned short* __restrict__ xb,    // [M, K] bf16 out
    unsigned short* __restrict__ wb)    // [N, K] bf16 out
{
    const int blk = blockIdx.x;
    if (blk < CVT_BLOCKS) {
        const size_t t = (size_t)blk * 256 + threadIdx.x;
        const f32x4* xv = (const f32x4*)x;
        f32x4 v0 = xv[2 * t];
        f32x4 v1 = xv[2 * t + 1];
        ushort8 r;
        r[0] = f2bf(v0[0]); r[1] = f2bf(v0[1]); r[2] = f2bf(v0[2]); r[3] = f2bf(v0[3]);
        r[4] = f2bf(v1[0]); r[5] = f2bf(v1[1]); r[6] = f2bf(v1[2]); r[7] = f2bf(v1[3]);
        ((ushort8*)xb)[t] = r;
    } else {
        const int t  = (blk - CVT_BLOCKS) * 256 + threadIdx.x;  // 0 .. N*(K/2)/4
        const int o  = t >> 9;                                  // 512 threads/row
        const int jp = (t & 511) << 2;                          // packed col base
        intx4 p = *(const intx4*)(packed + (size_t)o * (K_TOTAL / 2) + jp);
        const float s = scales[o];
        const size_t base = (size_t)o * K_TOTAL + (size_t)jp * 2;
        f32x4 g0 = *(const f32x4*)(ortho + base);
        f32x4 g1 = *(const f32x4*)(ortho + base + 4);
        float g[8] = { g0[0], g0[1], g0[2], g0[3], g1[0], g1[1], g1[2], g1[3] };
        ushort8 r;
#pragma unroll
        for (int i = 0; i < 4; ++i) {
            int pi = p[i];
            float lo = (float)((pi & 0xF) - 8) * s + g[2 * i];
            float hi = (float)(((pi >> 4) & 0xF) - 8) * s + g[2 * i + 1];
            r[2 * i]     = f2bf(lo);
            r[2 * i + 1] = f2bf(hi);
        }
        *(ushort8*)(wb + base) = r;
    }
}

// ---------------------------------------------------------------------------
// GEMM: C[M,N] = A[M,K](bf16) @ B[N,K](bf16)^T, fp32 accumulate.
// 256x256 tile, 8-phase schedule, counted vmcnt, setprio around MFMA.
// ---------------------------------------------------------------------------
__device__ __forceinline__ void async16(const void* g, void* l) {
    __builtin_amdgcn_global_load_lds(
        (__attribute__((address_space(1))) void*)(g),
        (__attribute__((address_space(3))) void*)(l),
        16, 0, 0);
}

__global__ __launch_bounds__(512, 2) void gemm256_kernel(
    const unsigned short* __restrict__ A,   // [M,K] bf16
    const unsigned short* __restrict__ Bm,  // [N,K] bf16
    float* __restrict__ C)                  // [M,N] fp32
{
    // 4 ring slots per matrix; slot = [256 rows][32 cols] bf16 = 8192 elems.
    __shared__ __attribute__((aligned(16))) unsigned short As[4 * 8192];
    __shared__ __attribute__((aligned(16))) unsigned short Bs[4 * 8192];

    const int tid  = threadIdx.x;
    const int wave = tid >> 6;
    const int lane = tid & 63;
    const int quad = lane >> 4;
    const int r16  = lane & 15;
    const int wm   = wave >> 2;      // 0..1  : wave M index (128 rows each)
    const int wn   = wave & 3;       // 0..3  : wave N index (64 cols each)

    const int row0 = blockIdx.y * 256;   // M origin
    const int col0 = blockIdx.x * 256;   // N origin

    // --- staging source (pre-swizzled: gload_lds dest is linear base+lane*16)
    // instruction covers 128 rows x 32 cols (8 KB); thread t -> row t>>2,
    // dest chunk t&3; source chunk = (t&3) ^ ((row>>1)&3) = (t&3)^((t>>3)&3).
    const int sr = tid >> 2;                       // 0..127
    const int cs = (tid & 3) ^ ((tid >> 3) & 3);   // swizzled source chunk
    const unsigned short* ag0 = A  + (size_t)(row0 + sr) * K_TOTAL + cs * 8;
    const unsigned short* ag1 = ag0 + (size_t)128 * K_TOTAL;
    const unsigned short* bg0 = Bm + (size_t)(col0 + sr) * K_TOTAL + cs * 8;
    const unsigned short* bg1 = bg0 + (size_t)128 * K_TOTAL;

    unsigned short* AsW = As + wave * 512;   // wave's 1 KB slice of each 8 KB half
    unsigned short* BsW = Bs + wave * 512;

#define STAGE_A(slot, kk) do { \
    async16(ag0 + (kk), AsW + (slot) * 8192); \
    async16(ag1 + (kk), AsW + (slot) * 8192 + 4096); } while (0)
#define STAGE_B(slot, kk) do { \
    async16(bg0 + (kk), BsW + (slot) * 8192); \
    async16(bg1 + (kk), BsW + (slot) * 8192 + 4096); } while (0)

    // --- fragment reads: row stride 32 elems (64 B); chunk read back through
    // the same XOR; frag offsets (m*16, wm*128) are ≡0 mod the swizzle period.
    const int swz   = (r16 >> 1) & 3;
    const int a_ofs = (wm * 128 + r16) * 32 + ((quad ^ swz) << 3);
    const int b_ofs = (wn * 64  + r16) * 32 + ((quad ^ swz) << 3);

#define LDA(slot, m) (*(const bf16x8*)(As + (slot) * 8192 + a_ofs + (m) * 512))
#define LDB(slot, n) (*(const bf16x8*)(Bs + (slot) * 8192 + b_ofs + (n) * 512))

    floatx4 acc[8][4] = {};

#define MROW(mi, ar) \
    acc[mi][0] = __builtin_amdgcn_mfma_f32_16x16x32_bf16(ar, b0, acc[mi][0], 0, 0, 0); \
    acc[mi][1] = __builtin_amdgcn_mfma_f32_16x16x32_bf16(ar, b1, acc[mi][1], 0, 0, 0); \
    acc[mi][2] = __builtin_amdgcn_mfma_f32_16x16x32_bf16(ar, b2, acc[mi][2], 0, 0, 0); \
    acc[mi][3] = __builtin_amdgcn_mfma_f32_16x16x32_bf16(ar, b3, acc[mi][3], 0, 0, 0);

    // One K=32 slice = 2 phases. Stage of slice s+3 (slot(s+3)=slot(s-1)) is
    // issued here, strictly after the barrier that closed slice s-1's reads.
    // VMW is the counted wait for slice s+1, before the closing barrier.
#define SLICE(slot, DOSTAGE, kkst, VMW) do { \
    bf16x8 b0 = LDB(slot, 0), b1 = LDB(slot, 1), b2 = LDB(slot, 2), b3 = LDB(slot, 3); \
    bf16x8 a0 = LDA(slot, 0), a1 = LDA(slot, 1), a2 = LDA(slot, 2), a3 = LDA(slot, 3); \
    if (DOSTAGE) STAGE_A(((slot) + 3) & 3, kkst); \
    __builtin_amdgcn_s_barrier(); \
    asm volatile("s_waitcnt lgkmcnt(0)"); \
    __builtin_amdgcn_s_setprio(1); \
    MROW(0, a0) MROW(1, a1) MROW(2, a2) MROW(3, a3) \
    __builtin_amdgcn_s_setprio(0); \
    __builtin_amdgcn_s_barrier(); \
    bf16x8 a4 = LDA(slot, 4), a5 = LDA(slot, 5), a6 = LDA(slot, 6), a7 = LDA(slot, 7); \
    if (DOSTAGE) STAGE_B(((slot) + 3) & 3, kkst); \
    __builtin_amdgcn_s_barrier(); \
    asm volatile("s_waitcnt lgkmcnt(0)"); \
    __builtin_amdgcn_s_setprio(1); \
    MROW(4, a4) MROW(5, a5) MROW(6, a6) MROW(7, a7) \
    __builtin_amdgcn_s_setprio(0); \
    asm volatile(VMW); \
    __builtin_amdgcn_s_barrier(); \
} while (0)

    // Prologue: fill the 4-slot ring (16 loads/wave), wait for slice 0 only.
    STAGE_A(0, 0);  STAGE_B(0, 0);
    STAGE_A(1, 32); STAGE_B(1, 32);
    STAGE_A(2, 64); STAGE_B(2, 64);
    STAGE_A(3, 96); STAGE_B(3, 96);
    asm volatile("s_waitcnt vmcnt(12)");
    __builtin_amdgcn_s_barrier();

    // Slices 0..3: slice 0 stages nothing (its target, slice 3, is prestaged).
    SLICE(0, 0, 0,      "s_waitcnt vmcnt(8)");
    SLICE(1, 1, 4 * 32, "s_waitcnt vmcnt(8)");
    SLICE(2, 1, 5 * 32, "s_waitcnt vmcnt(8)");
    SLICE(3, 1, 6 * 32, "s_waitcnt vmcnt(8)");

    // Steady state: slices 4..123, staging slices 7..126, vmcnt(8) per slice.
#pragma unroll 1
    for (int s4 = 4; s4 <= 120; s4 += 4) {
        const int kkb = (s4 + 3) * 32;
        SLICE(0, 1, kkb,      "s_waitcnt vmcnt(8)");
        SLICE(1, 1, kkb + 32, "s_waitcnt vmcnt(8)");
        SLICE(2, 1, kkb + 64, "s_waitcnt vmcnt(8)");
        SLICE(3, 1, kkb + 96, "s_waitcnt vmcnt(8)");
    }

    // Tail: slice 124 stages the last slice (127); drain 8 -> 4 -> 0.
    SLICE(0, 1, 127 * 32, "s_waitcnt vmcnt(8)");
    SLICE(1, 0, 0,        "s_waitcnt vmcnt(4)");
    SLICE(2, 0, 0,        "s_waitcnt vmcnt(0)");
    SLICE(3, 0, 0,        "");

#undef SLICE
#undef MROW
#undef LDA
#undef LDB
#undef STAGE_A
#undef STAGE_B

    // Epilogue. C/D layout (m89/m91-verified): col = lane&15, row = quad*4+reg.
    const int r_base = row0 + wm * 128 + quad * 4;
    const int c_base = col0 + wn * 64 + r16;
#pragma unroll
    for (int mi = 0; mi < 8; ++mi) {
#pragma unroll
        for (int ni = 0; ni < 4; ++ni) {
            const int r = r_base + mi * 16;
            const int c = c_base + ni * 16;
#pragma unroll
            for (int i = 0; i < 4; ++i)
                C[(size_t)(r + i) * N_TOTAL + c] = acc[mi][ni][i];
        }
    }
}

// ---------------------------------------------------------------------------
extern "C" void kernel_launch(void* const* d_in, const int* in_sizes, int n_in,
                              void* d_out, int out_size, void* d_ws, size_t ws_size,
                              hipStream_t stream) {
    const float* x      = (const float*)d_in[0];   // [4,2048,4096] fp32
    const int*   packed = (const int*)d_in[1];     // [4096,2048] int32
    const float* scales = (const float*)d_in[2];   // [4096,1] fp32
    const float* ortho  = (const float*)d_in[3];   // [4096,4096] fp32
    float*       out    = (float*)d_out;           // [4,2048,4096] fp32

    // Workspace layout: Xb (bf16, 64 MB) | Wb (bf16, 32 MB) = 96 MB total
    unsigned short* Xb = (unsigned short*)d_ws;
    unsigned short* Wb = (unsigned short*)((char*)d_ws + (size_t)M_TOTAL * K_TOTAL * 2);

    prep_kernel<<<CVT_BLOCKS + DEQ_BLOCKS, 256, 0, stream>>>(x, packed, scales, ortho, Xb, Wb);

    dim3 grid(N_TOTAL / 256, M_TOTAL / 256);  // (16, 32) = 512 blocks
    gemm256_kernel<<<grid, 512, 0, stream>>>(Xb, Wb, out);
}